// Round 15
// baseline (1375.416 us; speedup 1.0000x reference)
//
#include <hip/hip_runtime.h>
#include <hip/hip_bf16.h>

#define DEV __device__ __forceinline__

typedef __attribute__((ext_vector_type(8))) short bf16x8;
typedef __attribute__((ext_vector_type(4))) float f32x4;
typedef __attribute__((ext_vector_type(2))) float f32x2;

DEV f32x4 MF(bf16x8 a, bf16x8 b, f32x4 c) {
  return __builtin_amdgcn_mfma_f32_16x16x32_bf16(a, b, c, 0, 0, 0);
}

DEV float bf2f(unsigned short u) {
  union { unsigned int i; float f; } v; v.i = ((unsigned int)u) << 16; return v.f;
}
DEV unsigned short f2bf(float f) {
  __hip_bfloat16 h = __float2bfloat16(f);
  unsigned short r; __builtin_memcpy(&r, &h, 2); return r;
}
DEV unsigned int packbf(float a, float b) {
  float2 p; p.x = a; p.y = b;
  __hip_bfloat162 h = __float22bfloat162_rn(p);
  unsigned int r; __builtin_memcpy(&r, &h, 4); return r;
}
#define LOG2E 1.442695041f
#define LN2   0.6931471806f
DEV float silu_fast(float v) {
  float e = __builtin_amdgcn_exp2f(v * -LOG2E);
  return v * __builtin_amdgcn_rcpf(1.f + e);
}
DEV float softplus_fast(float v) {
  float e = __builtin_amdgcn_exp2f(v * LOG2E);
  float l = __builtin_amdgcn_logf(1.f + e) * LN2;
  return v > 15.f ? v : l;
}

// ws layout (bf16 element offsets)
#define WS_WINT   0        // 3 x [512][128]
#define WS_WXPT   196608   // 3 x [48][256] (cols 40..47 zero)
#define WS_WOUTT  233472   // 3 x [128][256]
#define WS_FF1T   331776   // 3 x [512][128]
#define WS_FF2T   528384   // 3 x [128][512]
#define WS_MIXT   724992   // [256][256]
#define WS_TOTAL  790528

// ---------------------------------------------------------------------------
// prep: transpose+convert all weight matrices into ws as bf16 [N][K]
// ---------------------------------------------------------------------------
__global__ __launch_bounds__(256) void prep_kernel(
    const float* __restrict__ w_in, const float* __restrict__ w_xp,
    const float* __restrict__ w_out, const float* __restrict__ ff1,
    const float* __restrict__ ff2, const float* __restrict__ mixw,
    unsigned short* __restrict__ ws)
{
  int idx = blockIdx.x * 256 + threadIdx.x;
  if (idx >= WS_TOTAL) return;
  float v;
  if (idx < WS_WXPT) {
    int j = idx, s = j / 65536, r = j % 65536, n = r >> 7, k = r & 127;
    v = w_in[s * 65536 + k * 512 + n];
  } else if (idx < WS_WOUTT) {
    int j = idx - WS_WXPT, s = j / 12288, r = j % 12288, n = r >> 8, k = r & 255;
    v = (n < 40) ? w_xp[s * 10240 + k * 40 + n] : 0.f;
  } else if (idx < WS_FF1T) {
    int j = idx - WS_WOUTT, s = j / 32768, r = j % 32768, n = r >> 8, k = r & 255;
    v = w_out[s * 32768 + k * 128 + n];
  } else if (idx < WS_FF2T) {
    int j = idx - WS_FF1T, s = j / 65536, r = j % 65536, n = r >> 7, k = r & 127;
    v = ff1[s * 65536 + k * 512 + n];
  } else if (idx < WS_MIXT) {
    int j = idx - WS_FF2T, s = j / 65536, r = j % 65536, n = r >> 9, k = r & 511;
    v = ff2[s * 65536 + k * 128 + n];
  } else {
    int j = idx - WS_MIXT, n = j >> 8, k = j & 255;
    v = mixw[k * 256 + n];
  }
  ws[idx] = f2bf(v);
}

// ---------------------------------------------------------------------------
// mamba_all, 3072 blocks:
//  blk in [0,1024): DOUBLE block (b,n): mamba(node) -> y in regs,
//    mamba(log) -> y; both into cs LDS; mix + residual+LN + FFN x2 -> final.
//  blk in [1024,3072): trace sequence: mamba + residual+LN + FFN -> final.
// 80KB LDS, 2 blocks/CU. The y round-trip through d_out is eliminated.
// ---------------------------------------------------------------------------
__global__ __launch_bounds__(256, 2) void mamba_all(
    const float* __restrict__ xn, const float* __restrict__ xt,
    const float* __restrict__ xl,
    const unsigned short* __restrict__ w_inT_all,
    const float* __restrict__ conv_w_all, const float* __restrict__ conv_b_all,
    const unsigned short* __restrict__ w_xpT_all,
    const float* __restrict__ dt_w_all, const float* __restrict__ dt_b_all,
    const float* __restrict__ Alog_all, const float* __restrict__ Dp_all,
    const unsigned short* __restrict__ w_outT_all,
    const unsigned short* __restrict__ mixT, const float* __restrict__ mix_b,
    const float* __restrict__ an_g, const float* __restrict__ an_b,
    const unsigned short* __restrict__ ff1T, const float* __restrict__ fb1,
    const unsigned short* __restrict__ ff2T, const float* __restrict__ fb2,
    const float* __restrict__ fln_g, const float* __restrict__ fln_b,
    float* __restrict__ out)
{
  __shared__ __attribute__((aligned(16))) unsigned short xcz[64 * 512]; // 64KB
  __shared__ __attribute__((aligned(16))) char aux[16384];              // 16KB
  unsigned short* xs = (unsigned short*)aux;      // [64][128] bf16 swizzled
  float* dbc = (float*)aux;                       // [64][48] f32
  unsigned short* cs = xcz;                       // [64][256] (after passes)
  unsigned short* hT2 = xcz + 64 * 256;           // [64][256] (ffn hidden, double path)

  const int tid = threadIdx.x;
  const int lane = tid & 63;
  const int wv = tid >> 6;
  const int lr = lane & 15;
  const int kg = lane >> 4;
  const int trow = wv * 16 + kg * 4;
  const int ta = wv * 16 + lr;

  const bool is_double = blockIdx.x < 1024;
  const int npass = is_double ? 2 : 1;
  int bD = 0, nD = 0, qT = 0;
  if (is_double) { bD = blockIdx.x >> 7; nD = blockIdx.x & 127; }
  else           { qT = blockIdx.x - 1024; }

  unsigned int ypk[16];   // node-pass y (packed bf16), live across pass 2

  for (int p = 0; p < npass; ++p) {
    // ---- per-pass stream setup ----
    int s;
    const float* x;
    int SEQ, b, n;
    if (is_double) {
      s = (p == 0) ? 0 : 2;
      x = (p == 0) ? xn : xl;
      SEQ = 128; b = bD; n = nD;
    } else {
      s = 1; x = xt; SEQ = 256; b = qT / 256; n = qT - b * 256;
    }
    const unsigned short* w_inT  = w_inT_all  + (size_t)s * 65536;
    const unsigned short* w_xpT  = w_xpT_all  + (size_t)s * 12288;
    const unsigned short* w_outT = w_outT_all + (size_t)s * 32768;
    const float* conv_w = conv_w_all + s * 1024;
    const float* conv_b = conv_b_all + s * 256;
    const float* dt_w   = dt_w_all + s * 2048;
    const float* dt_b   = dt_b_all + s * 256;
    const float* Alog   = Alog_all + s * 4096;
    const float* Dp     = Dp_all + s * 256;
    const float* xb = x + ((size_t)b * 64 * SEQ + n) * 128;

    // ---- stage x -> xs ----
    for (int idx = tid; idx < 2048; idx += 256) {
      int t = idx >> 5, qd = (idx & 31) << 2;
      float4 v = *(const float4*)(xb + (size_t)t * SEQ * 128 + qd);
      uint2 pk;
      pk.x = packbf(v.x, v.y);
      pk.y = packbf(v.z, v.w);
      *(uint2*)(&xs[t * 128 + (qd ^ ((t & 7) << 3))]) = pk;
    }
    __syncthreads();

    // ---- GEMM1 (swapped) -> xcz ----
    {
      bf16x8 bx[4][4];
#pragma unroll
      for (int jt = 0; jt < 4; ++jt)
#pragma unroll
        for (int ks = 0; ks < 4; ++ks) {
          int t = jt * 16 + lr;
          bx[jt][ks] = *(const bf16x8*)(&xs[t * 128 + ((ks * 32 + kg * 8) ^ ((t & 7) << 3))]);
        }
      const int nb = wv * 128;
#pragma unroll
      for (int at = 0; at < 8; ++at) {
        bf16x8 av[4];
        int arow = nb + at * 16 + lr;
#pragma unroll
        for (int ks = 0; ks < 4; ++ks)
          av[ks] = *(const bf16x8*)(w_inT + arow * 128 + ks * 32 + kg * 8);
#pragma unroll
        for (int jt = 0; jt < 4; ++jt) {
          f32x4 c = {0.f, 0.f, 0.f, 0.f};
#pragma unroll
          for (int ks = 0; ks < 4; ++ks) c = MF(av[ks], bx[jt][ks], c);
          int t = jt * 16 + lr;
          int n0 = nb + at * 16 + kg * 4;
          uint2 pk;
          pk.x = packbf(c[0], c[1]);
          pk.y = packbf(c[2], c[3]);
          *(uint2*)(&xcz[t * 512 + (n0 ^ ((t & 7) << 3))]) = pk;
        }
      }
    }
    __syncthreads();

    // ---- conv + bias + silu ----
    {
      const int d = tid;
      float cw0 = conv_w[d * 4 + 0], cw1 = conv_w[d * 4 + 1];
      float cw2 = conv_w[d * 4 + 2], cw3 = conv_w[d * 4 + 3];
      float cb = conv_b[d];
      float xm3 = 0.f, xm2 = 0.f, xm1 = 0.f;
      for (int c0 = 0; c0 < 64; c0 += 16) {
        float xv[16];
#pragma unroll
        for (int u = 0; u < 16; ++u) {
          int t = c0 + u;
          xv[u] = bf2f(xcz[t * 512 + (d ^ ((t & 7) << 3))]);
        }
#pragma unroll
        for (int u = 0; u < 16; ++u) {
          float sv = fmaf(cw0, xm3, fmaf(cw1, xm2, fmaf(cw2, xm1, fmaf(cw3, xv[u], cb))));
          xm3 = xm2; xm2 = xm1; xm1 = xv[u];
          xv[u] = silu_fast(sv);
        }
#pragma unroll
        for (int u = 0; u < 16; ++u) {
          int t = c0 + u;
          xcz[t * 512 + (d ^ ((t & 7) << 3))] = f2bf(xv[u]);
        }
      }
    }
    __syncthreads();

    // ---- x_proj -> dbc ----
    {
      bf16x8 av[8];
#pragma unroll
      for (int ks = 0; ks < 8; ++ks)
        av[ks] = *(const bf16x8*)(&xcz[ta * 512 + ((ks * 32 + kg * 8) ^ ((ta & 7) << 3))]);
#pragma unroll
      for (int ct = 0; ct < 3; ++ct) {
        f32x4 c = {0.f, 0.f, 0.f, 0.f};
#pragma unroll
        for (int ks = 0; ks < 8; ++ks) {
          bf16x8 bv = *(const bf16x8*)(w_xpT + (ct * 16 + lr) * 256 + ks * 32 + kg * 8);
          c = MF(av[ks], bv, c);
        }
        int tt = wv * 16 + kg * 4;
#pragma unroll
        for (int r = 0; r < 4; ++r)
          dbc[(tt + r) * 48 + ct * 16 + lr] = c[r];
      }
    }
    __syncthreads();

    // ---- selective scan + gate ----
    {
      const int d = tid;
      float dtw[8];
#pragma unroll
      for (int r = 0; r < 8; ++r) dtw[r] = dt_w[r * 256 + d];
      const float dtb = dt_b[d];
      float Af2[16];
#pragma unroll
      for (int s2 = 0; s2 < 16; ++s2)
        Af2[s2] = -__builtin_amdgcn_exp2f(Alog[d * 16 + s2] * LOG2E) * LOG2E;
      const float af0l2 = Af2[0];
      bool geo = true;
#pragma unroll
      for (int s2 = 1; s2 < 16; ++s2)
        geo = geo && (fabsf(Af2[s2] - (float)(s2 + 1) * af0l2) <= 2e-4f * fabsf(Af2[s2]));
      const float Dv = Dp[d];
      const int eoff = d;
      const int zoff = 256 + d;

      if (geo) {
        f32x2 h2[8];
#pragma unroll
        for (int k = 0; k < 8; ++k) h2[k] = (f32x2){0.f, 0.f};
#pragma unroll 2
        for (int t = 0; t < 64; ++t) {
          const f32x4* dr4 = (const f32x4*)&dbc[t * 48];
          f32x4 d0 = dr4[0], d1 = dr4[1];
          float dtv = dtb;
          dtv = fmaf(dtw[0], d0[0], dtv); dtv = fmaf(dtw[1], d0[1], dtv);
          dtv = fmaf(dtw[2], d0[2], dtv); dtv = fmaf(dtw[3], d0[3], dtv);
          dtv = fmaf(dtw[4], d1[0], dtv); dtv = fmaf(dtw[5], d1[1], dtv);
          dtv = fmaf(dtw[6], d1[2], dtv); dtv = fmaf(dtw[7], d1[3], dtv);
          dtv = softplus_fast(dtv);
          int sw = (t & 7) << 3;
          int e = t * 512 + (eoff ^ sw);
          float xv = bf2f(xcz[e]);
          float zf = bf2f(xcz[t * 512 + (zoff ^ sw)]);
          float cf = dtv * xv;
          float r1 = __builtin_amdgcn_exp2f(dtv * af0l2);
          float r2 = r1 * r1;
          f32x2 r2v = {r2, r2};
          f32x2 pp = {r1, r2};
          f32x2 cf2 = {cf, cf};
          f32x2 y2 = {0.f, 0.f};
          f32x4 B0 = dr4[2], B1 = dr4[3], B2 = dr4[4], B3 = dr4[5];
          f32x4 C0 = dr4[6], C1 = dr4[7], C2 = dr4[8], C3 = dr4[9];
          f32x2 Bv[8] = {{B0[0],B0[1]},{B0[2],B0[3]},{B1[0],B1[1]},{B1[2],B1[3]},
                         {B2[0],B2[1]},{B2[2],B2[3]},{B3[0],B3[1]},{B3[2],B3[3]}};
          f32x2 Cv[8] = {{C0[0],C0[1]},{C0[2],C0[3]},{C1[0],C1[1]},{C1[2],C1[3]},
                         {C2[0],C2[1]},{C2[2],C2[3]},{C3[0],C3[1]},{C3[2],C3[3]}};
#pragma unroll
          for (int k = 0; k < 8; ++k) {
            h2[k] = __builtin_elementwise_fma(pp, h2[k], cf2 * Bv[k]);
            y2 = __builtin_elementwise_fma(h2[k], Cv[k], y2);
            pp = pp * r2v;
          }
          float y = y2[0] + y2[1];
          xcz[e] = f2bf((fmaf(xv, Dv, y)) * silu_fast(zf));
        }
      } else {
        float h[16];
#pragma unroll
        for (int s2 = 0; s2 < 16; ++s2) h[s2] = 0.f;
#pragma unroll 2
        for (int t = 0; t < 64; ++t) {
          const float* dr = &dbc[t * 48];
          float dtv = dtb;
#pragma unroll
          for (int r = 0; r < 8; ++r) dtv = fmaf(dtw[r], dr[r], dtv);
          dtv = softplus_fast(dtv);
          int sw = (t & 7) << 3;
          int e = t * 512 + (eoff ^ sw);
          float xv = bf2f(xcz[e]);
          float zf = bf2f(xcz[t * 512 + (zoff ^ sw)]);
          float cf = dtv * xv;
          float y = 0.f;
#pragma unroll
          for (int s2 = 0; s2 < 16; ++s2) {
            float dA = __builtin_amdgcn_exp2f(dtv * Af2[s2]);
            h[s2] = fmaf(dA, h[s2], cf * dr[8 + s2]);
            y = fmaf(h[s2], dr[24 + s2], y);
          }
          xcz[e] = f2bf((fmaf(xv, Dv, y)) * silu_fast(zf));
        }
      }
    }
    __syncthreads();

    // ---- GEMM-out ----
    {
      bf16x8 av[8];
#pragma unroll
      for (int ks = 0; ks < 8; ++ks)
        av[ks] = *(const bf16x8*)(&xcz[ta * 512 + ((ks * 32 + kg * 8) ^ ((ta & 7) << 3))]);
      f32x4 acc[8];
#pragma unroll
      for (int ct = 0; ct < 8; ++ct) {
        f32x4 c = {0.f, 0.f, 0.f, 0.f};
#pragma unroll
        for (int ks = 0; ks < 8; ++ks) {
          bf16x8 bv = *(const bf16x8*)(w_outT + (ct * 16 + lr) * 256 + ks * 32 + kg * 8);
          c = MF(av[ks], bv, c);
        }
        acc[ct] = c;
      }

      if (is_double) {
        if (p == 0) {
          // node pass: park y in regs (bf16 packed)
#pragma unroll
          for (int ct = 0; ct < 8; ++ct) {
            ypk[ct * 2 + 0] = packbf(acc[ct][0], acc[ct][1]);
            ypk[ct * 2 + 1] = packbf(acc[ct][2], acc[ct][3]);
          }
        } else {
          // log pass: wait for all xcz reads, then build cs=[yn||yl]
          __syncthreads();
#pragma unroll
          for (int ct = 0; ct < 8; ++ct) {
            int col = ct * 16 + lr;
#pragma unroll
            for (int r = 0; r < 4; ++r) {
              int t = trow + r;
              int sw = (t & 7) << 3;
              unsigned int pk = ypk[ct * 2 + (r >> 1)];
              unsigned short yn16 = (r & 1) ? (unsigned short)(pk >> 16)
                                            : (unsigned short)(pk & 0xffff);
              cs[t * 256 + (col ^ sw)] = yn16;                       // node half
              cs[t * 256 + ((128 + col) ^ sw)] = f2bf(acc[ct][r]);   // log half
            }
          }
        }
      } else {
        // trace: residual + LN(an[1]) -> t1 in xs, then FFN (stream 1)
        const float* xb2 = xt + ((size_t)b * 64 * 256 + n) * 128;
        size_t ob = (size_t)b * 64 * 512 * 128 + (size_t)(128 + n) * 128;
        float sum[4] = {0.f, 0.f, 0.f, 0.f}, sq[4] = {0.f, 0.f, 0.f, 0.f};
#pragma unroll
        for (int ct = 0; ct < 8; ++ct) {
          int col = ct * 16 + lr;
#pragma unroll
          for (int r = 0; r < 4; ++r) {
            int t = trow + r;
            float xr = xb2[(size_t)t * 256 * 128 + col];
            float v = acc[ct][r] + xr;
            acc[ct][r] = v;
            sum[r] += v; sq[r] += v * v;
          }
        }
        float mn[4], rstd[4];
#pragma unroll
        for (int r = 0; r < 4; ++r) {
          float s1 = sum[r], s2 = sq[r];
          s1 += __shfl_xor(s1, 1); s2 += __shfl_xor(s2, 1);
          s1 += __shfl_xor(s1, 2); s2 += __shfl_xor(s2, 2);
          s1 += __shfl_xor(s1, 4); s2 += __shfl_xor(s2, 4);
          s1 += __shfl_xor(s1, 8); s2 += __shfl_xor(s2, 8);
          float mean = s1 * (1.f / 128.f);
          float var = s2 * (1.f / 128.f) - mean * mean;
          mn[r] = mean;
          rstd[r] = rsqrtf(var + 1e-5f);
        }
        const float* G  = an_g + 128;
        const float* Bv = an_b + 128;
#pragma unroll
        for (int ct = 0; ct < 8; ++ct) {
          int col = ct * 16 + lr;
          float gc = G[col], bc = Bv[col];
#pragma unroll
          for (int r = 0; r < 4; ++r) {
            int t = trow + r;
            float t1 = (acc[ct][r] - mn[r]) * rstd[r] * gc + bc;
            xs[t * 128 + (col ^ ((t & 7) << 3))] = f2bf(t1);
          }
        }
        __syncthreads();

        const unsigned short* F1 = ff1T + 65536;
        const unsigned short* F2 = ff2T + 65536;
        const float* B1 = fb1 + 512;
        const float* B2 = fb2 + 128;
        const float* FG = fln_g + 128;
        const float* FB = fln_b + 128;
        {
          bf16x8 bx[4][4];
#pragma unroll
          for (int jt = 0; jt < 4; ++jt)
#pragma unroll
            for (int ks = 0; ks < 4; ++ks) {
              int t = jt * 16 + lr;
              bx[jt][ks] = *(const bf16x8*)(&xs[t * 128 + ((ks * 32 + kg * 8) ^ ((t & 7) << 3))]);
            }
          const int nb = wv * 128;
#pragma unroll
          for (int at = 0; at < 8; ++at) {
            bf16x8 av1[4];
            int arow = nb + at * 16 + lr;
#pragma unroll
            for (int ks = 0; ks < 4; ++ks)
              av1[ks] = *(const bf16x8*)(F1 + arow * 128 + ks * 32 + kg * 8);
            float4 bias = *(const float4*)(B1 + nb + at * 16 + kg * 4);
#pragma unroll
            for (int jt = 0; jt < 4; ++jt) {
              f32x4 c = {0.f, 0.f, 0.f, 0.f};
#pragma unroll
              for (int ks = 0; ks < 4; ++ks) c = MF(av1[ks], bx[jt][ks], c);
              float v0 = c[0] + bias.x; v0 = v0 > 0.f ? v0 : 0.01f * v0;
              float v1 = c[1] + bias.y; v1 = v1 > 0.f ? v1 : 0.01f * v1;
              float v2 = c[2] + bias.z; v2 = v2 > 0.f ? v2 : 0.01f * v2;
              float v3 = c[3] + bias.w; v3 = v3 > 0.f ? v3 : 0.01f * v3;
              int t = jt * 16 + lr;
              int n0 = nb + at * 16 + kg * 4;
              uint2 pk;
              pk.x = packbf(v0, v1);
              pk.y = packbf(v2, v3);
              *(uint2*)(&xcz[t * 512 + (n0 ^ ((t & 7) << 3))]) = pk;
            }
          }
        }
        __syncthreads();
        {
          bf16x8 av2[16];
#pragma unroll
          for (int ks = 0; ks < 16; ++ks)
            av2[ks] = *(const bf16x8*)(&xcz[ta * 512 + ((ks * 32 + kg * 8) ^ ((ta & 7) << 3))]);
          f32x4 a2[8];
#pragma unroll
          for (int ct = 0; ct < 8; ++ct) {
            f32x4 c = {0.f, 0.f, 0.f, 0.f};
#pragma unroll
            for (int ks = 0; ks < 16; ++ks) {
              bf16x8 bv = *(const bf16x8*)(F2 + (ct * 16 + lr) * 512 + ks * 32 + kg * 8);
              c = MF(av2[ks], bv, c);
            }
            a2[ct] = c;
          }
          float vv[8][4];
          float su[4] = {0.f, 0.f, 0.f, 0.f}, sb[4] = {0.f, 0.f, 0.f, 0.f};
#pragma unroll
          for (int ct = 0; ct < 8; ++ct) {
            int col = ct * 16 + lr;
            float b2c = B2[col];
#pragma unroll
            for (int r = 0; r < 4; ++r) {
              int t = trow + r;
              float xr = bf2f(xs[t * 128 + (col ^ ((t & 7) << 3))]);
              float val = a2[ct][r] + b2c + xr;
              vv[ct][r] = val;
              su[r] += val; sb[r] += val * val;
            }
          }
          float mn2[4], rs2[4];
#pragma unroll
          for (int r = 0; r < 4; ++r) {
            float s1 = su[r], s2 = sb[r];
            s1 += __shfl_xor(s1, 1); s2 += __shfl_xor(s2, 1);
            s1 += __shfl_xor(s1, 2); s2 += __shfl_xor(s2, 2);
            s1 += __shfl_xor(s1, 4); s2 += __shfl_xor(s2, 4);
            s1 += __shfl_xor(s1, 8); s2 += __shfl_xor(s2, 8);
            float mean = s1 * (1.f / 128.f);
            float var = s2 * (1.f / 128.f) - mean * mean;
            mn2[r] = mean;
            rs2[r] = rsqrtf(var + 1e-5f);
          }
#pragma unroll
          for (int ct = 0; ct < 8; ++ct) {
            int col = ct * 16 + lr;
            float gc = FG[col], bc = FB[col];
#pragma unroll
            for (int r = 0; r < 4; ++r)
              out[ob + (size_t)(trow + r) * 65536 + col] = (vv[ct][r] - mn2[r]) * rs2[r] * gc + bc;
          }
        }
      }
    }
  } // pass loop

  if (!is_double) return;

  // =========== double path: mix + residual + LN + FFN x2 from cs ===========
  __syncthreads();
  const size_t base_n = (((size_t)bD * 64) * 512 + nD) * 128;
  const size_t base_l = (((size_t)bD * 64) * 512 + 384 + nD) * 128;

  bf16x8 av[8];
#pragma unroll
  for (int ks = 0; ks < 8; ++ks)
    av[ks] = *(const bf16x8*)(&cs[ta * 256 + ((ks * 32 + kg * 8) ^ ((ta & 7) << 3))]);

#pragma unroll
  for (int half = 0; half < 2; ++half) {
    const int sf = half ? 2 : 0;
    const float* xres_base = half ? xl : xn;
    f32x4 acc[8];
#pragma unroll
    for (int ct = 0; ct < 8; ++ct) {
      f32x4 c = {0.f, 0.f, 0.f, 0.f};
      int colg = half * 128 + ct * 16 + lr;
#pragma unroll
      for (int ks = 0; ks < 8; ++ks) {
        bf16x8 bv = *(const bf16x8*)(mixT + colg * 256 + ks * 32 + kg * 8);
        c = MF(av[ks], bv, c);
      }
      acc[ct] = c;
    }
    float sum[4] = {0.f, 0.f, 0.f, 0.f}, sq[4] = {0.f, 0.f, 0.f, 0.f};
#pragma unroll
    for (int ct = 0; ct < 8; ++ct) {
      int col = ct * 16 + lr;
      int colg = half * 128 + col;
      float bcol = mix_b[colg];
#pragma unroll
      for (int r = 0; r < 4; ++r) {
        int t = trow + r;
        float orig = bf2f(cs[t * 256 + (colg ^ ((t & 7) << 3))]);
        float xr = xres_base[(((size_t)bD * 64 + t) * 128 + nD) * 128 + col];
        float v = orig + silu_fast(acc[ct][r] + bcol) + xr;
        acc[ct][r] = v;
        sum[r] += v; sq[r] += v * v;
      }
    }
    float mn[4], rstd[4];
#pragma unroll
    for (int r = 0; r < 4; ++r) {
      float s1 = sum[r], s2 = sq[r];
      s1 += __shfl_xor(s1, 1); s2 += __shfl_xor(s2, 1);
      s1 += __shfl_xor(s1, 2); s2 += __shfl_xor(s2, 2);
      s1 += __shfl_xor(s1, 4); s2 += __shfl_xor(s2, 4);
      s1 += __shfl_xor(s1, 8); s2 += __shfl_xor(s2, 8);
      float mean = s1 * (1.f / 128.f);
      float var = s2 * (1.f / 128.f) - mean * mean;
      mn[r] = mean;
      rstd[r] = rsqrtf(var + 1e-5f);
    }
    {
      const float* G  = an_g + (half ? 256 : 0);
      const float* Bv = an_b + (half ? 256 : 0);
#pragma unroll
      for (int ct = 0; ct < 8; ++ct) {
        int col = ct * 16 + lr;
        float gc = G[col], bc = Bv[col];
#pragma unroll
        for (int r = 0; r < 4; ++r) {
          int t = trow + r;
          float n1 = (acc[ct][r] - mn[r]) * rstd[r] * gc + bc;
          xs[t * 128 + (col ^ ((t & 7) << 3))] = f2bf(n1);
        }
      }
    }
    __syncthreads();

    const unsigned short* F1 = ff1T + (size_t)sf * 65536;
    const unsigned short* F2 = ff2T + (size_t)sf * 65536;
    const float* B1 = fb1 + sf * 512;
    const float* B2 = fb2 + sf * 128;
    const float* FG = fln_g + sf * 128;
    const float* FB = fln_b + sf * 128;

    bf16x8 bx[4][4];
#pragma unroll
    for (int jt = 0; jt < 4; ++jt)
#pragma unroll
      for (int ks = 0; ks < 4; ++ks) {
        int t = jt * 16 + lr;
        bx[jt][ks] = *(const bf16x8*)(&xs[t * 128 + ((ks * 32 + kg * 8) ^ ((t & 7) << 3))]);
      }

    f32x4 acc2[8];
#pragma unroll
    for (int ct = 0; ct < 8; ++ct) acc2[ct] = (f32x4){0.f, 0.f, 0.f, 0.f};

#pragma unroll
    for (int kh = 0; kh < 2; ++kh) {
      const int nb = kh * 256 + wv * 64;
#pragma unroll
      for (int at = 0; at < 4; ++at) {
        bf16x8 av1[4];
        int arow = nb + at * 16 + lr;
#pragma unroll
        for (int ks = 0; ks < 4; ++ks)
          av1[ks] = *(const bf16x8*)(F1 + arow * 128 + ks * 32 + kg * 8);
        float4 bias = *(const float4*)(B1 + nb + at * 16 + kg * 4);
#pragma unroll
        for (int jt = 0; jt < 4; ++jt) {
          f32x4 c = {0.f, 0.f, 0.f, 0.f};
#pragma unroll
          for (int ks = 0; ks < 4; ++ks) c = MF(av1[ks], bx[jt][ks], c);
          float v0 = c[0] + bias.x; v0 = v0 > 0.f ? v0 : 0.01f * v0;
          float v1 = c[1] + bias.y; v1 = v1 > 0.f ? v1 : 0.01f * v1;
          float v2 = c[2] + bias.z; v2 = v2 > 0.f ? v2 : 0.01f * v2;
          float v3 = c[3] + bias.w; v3 = v3 > 0.f ? v3 : 0.01f * v3;
          int t = jt * 16 + lr;
          int nl = wv * 64 + at * 16 + kg * 4;
          uint2 pk;
          pk.x = packbf(v0, v1);
          pk.y = packbf(v2, v3);
          *(uint2*)(&hT2[t * 256 + (nl ^ ((t & 7) << 3))]) = pk;
        }
      }
      __syncthreads();

      bf16x8 av2[8];
#pragma unroll
      for (int ks = 0; ks < 8; ++ks)
        av2[ks] = *(const bf16x8*)(&hT2[ta * 256 + ((ks * 32 + kg * 8) ^ ((ta & 7) << 3))]);
#pragma unroll
      for (int ct = 0; ct < 8; ++ct) {
        f32x4 c = acc2[ct];
#pragma unroll
        for (int ks = 0; ks < 8; ++ks) {
          bf16x8 bv = *(const bf16x8*)(F2 + (ct * 16 + lr) * 512 + kh * 256 + ks * 32 + kg * 8);
          c = MF(av2[ks], bv, c);
        }
        acc2[ct] = c;
      }
      __syncthreads();
    }

    {
      float vv[8][4];
      float su[4] = {0.f, 0.f, 0.f, 0.f}, sb[4] = {0.f, 0.f, 0.f, 0.f};
#pragma unroll
      for (int ct = 0; ct < 8; ++ct) {
        int col = ct * 16 + lr;
        float b2c = B2[col];
#pragma unroll
        for (int r = 0; r < 4; ++r) {
          int t = trow + r;
          float xr = bf2f(xs[t * 128 + (col ^ ((t & 7) << 3))]);
          float val = acc2[ct][r] + b2c + xr;
          vv[ct][r] = val;
          su[r] += val; sb[r] += val * val;
        }
      }
      float mn2[4], rs2[4];
#pragma unroll
      for (int r = 0; r < 4; ++r) {
        float s1 = su[r], s2 = sb[r];
        s1 += __shfl_xor(s1, 1); s2 += __shfl_xor(s2, 1);
        s1 += __shfl_xor(s1, 2); s2 += __shfl_xor(s2, 2);
        s1 += __shfl_xor(s1, 4); s2 += __shfl_xor(s2, 4);
        s1 += __shfl_xor(s1, 8); s2 += __shfl_xor(s2, 8);
        float mean = s1 * (1.f / 128.f);
        float var = s2 * (1.f / 128.f) - mean * mean;
        mn2[r] = mean;
        rs2[r] = rsqrtf(var + 1e-5f);
      }
      size_t base = half ? base_l : base_n;
#pragma unroll
      for (int ct = 0; ct < 8; ++ct) {
        int col = ct * 16 + lr;
        float gc = FG[col], bc = FB[col];
#pragma unroll
        for (int r = 0; r < 4; ++r)
          out[base + (size_t)(trow + r) * 65536 + col] = (vv[ct][r] - mn2[r]) * rs2[r] * gc + bc;
      }
    }
    __syncthreads();
  }
}

extern "C" void kernel_launch(void* const* d_in, const int* in_sizes, int n_in,
                              void* d_out, int out_size, void* d_ws, size_t ws_size,
                              hipStream_t stream) {
  (void)in_sizes; (void)n_in; (void)out_size; (void)ws_size;
  const float* x_node  = (const float*)d_in[0];
  const float* x_trace = (const float*)d_in[1];
  const float* x_log   = (const float*)d_in[2];
  const float* mp_in     = (const float*)d_in[3];
  const float* mp_conv_w = (const float*)d_in[4];
  const float* mp_conv_b = (const float*)d_in[5];
  const float* mp_xproj  = (const float*)d_in[6];
  const float* mp_dt_w   = (const float*)d_in[7];
  const float* mp_dt_b   = (const float*)d_in[8];
  const float* mp_Alog   = (const float*)d_in[9];
  const float* mp_D      = (const float*)d_in[10];
  const float* mp_out    = (const float*)d_in[11];
  const float* mix_w = (const float*)d_in[12];
  const float* mix_b = (const float*)d_in[13];
  const float* an_g  = (const float*)d_in[14];
  const float* an_b  = (const float*)d_in[15];
  const float* ff1_w = (const float*)d_in[16];
  const float* ff1_b = (const float*)d_in[17];
  const float* ff2_w = (const float*)d_in[18];
  const float* ff2_b = (const float*)d_in[19];
  const float* fln_g = (const float*)d_in[20];
  const float* fln_b = (const float*)d_in[21];
  float* out = (float*)d_out;

  unsigned short* ws = (unsigned short*)d_ws;

  prep_kernel<<<(WS_TOTAL + 255) / 256, 256, 0, stream>>>(
      mp_in, mp_xproj, mp_out, ff1_w, ff2_w, mix_w, ws);

  mamba_all<<<3072, 256, 0, stream>>>(
      x_node, x_trace, x_log,
      ws + WS_WINT, mp_conv_w, mp_conv_b, ws + WS_WXPT,
      mp_dt_w, mp_dt_b, mp_Alog, mp_D, ws + WS_WOUTT,
      ws + WS_MIXT, mix_b, an_g, an_b,
      ws + WS_FF1T, ff1_b, ws + WS_FF2T, ff2_b, fln_g, fln_b,
      out);
}

// Round 16
// 791.916 us; speedup vs baseline: 1.7368x; 1.7368x over previous
//
#include <hip/hip_runtime.h>
#include <hip/hip_bf16.h>

#define DEV __device__ __forceinline__

typedef __attribute__((ext_vector_type(8))) short bf16x8;
typedef __attribute__((ext_vector_type(4))) float f32x4;
typedef __attribute__((ext_vector_type(2))) float f32x2;

DEV f32x4 MF(bf16x8 a, bf16x8 b, f32x4 c) {
  return __builtin_amdgcn_mfma_f32_16x16x32_bf16(a, b, c, 0, 0, 0);
}

DEV float bf2f(unsigned short u) {
  union { unsigned int i; float f; } v; v.i = ((unsigned int)u) << 16; return v.f;
}
DEV unsigned short f2bf(float f) {
  __hip_bfloat16 h = __float2bfloat16(f);
  unsigned short r; __builtin_memcpy(&r, &h, 2); return r;
}
DEV unsigned int packbf(float a, float b) {
  float2 p; p.x = a; p.y = b;
  __hip_bfloat162 h = __float22bfloat162_rn(p);
  unsigned int r; __builtin_memcpy(&r, &h, 4); return r;
}
#define LOG2E 1.442695041f
#define LN2   0.6931471806f
DEV float silu_fast(float v) {
  float e = __builtin_amdgcn_exp2f(v * -LOG2E);
  return v * __builtin_amdgcn_rcpf(1.f + e);
}
DEV float softplus_fast(float v) {
  float e = __builtin_amdgcn_exp2f(v * LOG2E);
  float l = __builtin_amdgcn_logf(1.f + e) * LN2;
  return v > 15.f ? v : l;
}

// ws layout (bf16 element offsets)
#define WS_WINT   0        // 3 x [512][128]
#define WS_WXPT   196608   // 3 x [48][256] (cols 40..47 zero)
#define WS_WOUTT  233472   // 3 x [128][256]
#define WS_FF1T   331776   // 3 x [512][128]
#define WS_FF2T   528384   // 3 x [128][512]
#define WS_MIXT   724992   // [256][256]
#define WS_TOTAL  790528

// ---------------------------------------------------------------------------
// prep: transpose+convert all weight matrices into ws as bf16 [N][K]
// ---------------------------------------------------------------------------
__global__ __launch_bounds__(256) void prep_kernel(
    const float* __restrict__ w_in, const float* __restrict__ w_xp,
    const float* __restrict__ w_out, const float* __restrict__ ff1,
    const float* __restrict__ ff2, const float* __restrict__ mixw,
    unsigned short* __restrict__ ws)
{
  int idx = blockIdx.x * 256 + threadIdx.x;
  if (idx >= WS_TOTAL) return;
  float v;
  if (idx < WS_WXPT) {              // w_inT [s][512][128]
    int j = idx, s = j / 65536, r = j % 65536, n = r >> 7, k = r & 127;
    v = w_in[s * 65536 + k * 512 + n];
  } else if (idx < WS_WOUTT) {      // w_xpT [s][48][256]
    int j = idx - WS_WXPT, s = j / 12288, r = j % 12288, n = r >> 8, k = r & 255;
    v = (n < 40) ? w_xp[s * 10240 + k * 40 + n] : 0.f;
  } else if (idx < WS_FF1T) {       // w_outT [s][128][256]
    int j = idx - WS_WOUTT, s = j / 32768, r = j % 32768, n = r >> 8, k = r & 255;
    v = w_out[s * 32768 + k * 128 + n];
  } else if (idx < WS_FF2T) {       // ff1T [s][512][128]
    int j = idx - WS_FF1T, s = j / 65536, r = j % 65536, n = r >> 7, k = r & 127;
    v = ff1[s * 65536 + k * 512 + n];
  } else if (idx < WS_MIXT) {       // ff2T [s][128][512]
    int j = idx - WS_FF2T, s = j / 65536, r = j % 65536, n = r >> 9, k = r & 511;
    v = ff2[s * 65536 + k * 128 + n];
  } else {                          // mixT [256][256]
    int j = idx - WS_MIXT, n = j >> 8, k = j & 255;
    v = mixw[k * 256 + n];
  }
  ws[idx] = f2bf(v);
}

// ---------------------------------------------------------------------------
// Fused mamba front, all 3 streams. One block = one sequence. 80KB LDS.
// Trace (s==1): + residual + LN(an[1]) + FULL FFN(stream 1) + LN(fln[1]),
// writing final t2 — trace slots of d_out are written once, never re-read.
// ---------------------------------------------------------------------------
__global__ __launch_bounds__(256, 2) void mamba_front(
    const float* __restrict__ xn, const float* __restrict__ xt,
    const float* __restrict__ xl,
    const unsigned short* __restrict__ w_inT_all,
    const float* __restrict__ conv_w_all, const float* __restrict__ conv_b_all,
    const unsigned short* __restrict__ w_xpT_all,
    const float* __restrict__ dt_w_all, const float* __restrict__ dt_b_all,
    const float* __restrict__ Alog_all, const float* __restrict__ Dp_all,
    const unsigned short* __restrict__ w_outT_all,
    const float* __restrict__ an_g, const float* __restrict__ an_b,
    const unsigned short* __restrict__ ff1T, const float* __restrict__ fb1,
    const unsigned short* __restrict__ ff2T, const float* __restrict__ fb2,
    const float* __restrict__ fln_g, const float* __restrict__ fln_b,
    float* __restrict__ out)
{
  __shared__ __attribute__((aligned(16))) unsigned short xcz[64 * 512]; // 64KB; later hT
  __shared__ __attribute__((aligned(16))) char aux[16384];              // 16KB
  unsigned short* xs = (unsigned short*)aux;   // [64][128] bf16 swizzled (x, later t1)
  float* dbc = (float*)aux;                    // [64][48] f32 (x_proj output)

  const int tid = threadIdx.x;
  const int lane = tid & 63;
  const int wv = tid >> 6;
  const int lr = lane & 15;
  const int kg = lane >> 4;

  int blk = blockIdx.x, s, q;
  if (blk < 1024)      { s = 0; q = blk; }
  else if (blk < 3072) { s = 1; q = blk - 1024; }
  else                 { s = 2; q = blk - 3072; }
  const int SEQ = (s == 1) ? 256 : 128;
  const int slot_base = (s == 0) ? 0 : (s == 1 ? 128 : 384);
  const float* x = (s == 0) ? xn : (s == 1 ? xt : xl);
  const unsigned short* w_inT  = w_inT_all  + (size_t)s * 65536;
  const unsigned short* w_xpT  = w_xpT_all  + (size_t)s * 12288;
  const unsigned short* w_outT = w_outT_all + (size_t)s * 32768;
  const float* conv_w = conv_w_all + s * 1024;
  const float* conv_b = conv_b_all + s * 256;
  const float* dt_w   = dt_w_all + s * 2048;
  const float* dt_b   = dt_b_all + s * 256;
  const float* Alog   = Alog_all + s * 4096;
  const float* Dp     = Dp_all + s * 256;

  const int b = q / SEQ, n = q - b * SEQ;
  const float* xb = x + ((size_t)b * 64 * SEQ + n) * 128;

  // stage x -> xs (bf16, XOR-swizzled)
  for (int idx = tid; idx < 2048; idx += 256) {
    int t = idx >> 5, qd = (idx & 31) << 2;
    float4 v = *(const float4*)(xb + (size_t)t * SEQ * 128 + qd);
    uint2 p;
    p.x = packbf(v.x, v.y);
    p.y = packbf(v.z, v.w);
    *(uint2*)(&xs[t * 128 + (qd ^ ((t & 7) << 3))]) = p;
  }
  __syncthreads();

  // GEMM1 (swapped): xz^T[n][t] = w_inT[n][:] . x[t][:]
  {
    bf16x8 bx[4][4];
#pragma unroll
    for (int jt = 0; jt < 4; ++jt)
#pragma unroll
      for (int ks = 0; ks < 4; ++ks) {
        int t = jt * 16 + lr;
        bx[jt][ks] = *(const bf16x8*)(&xs[t * 128 + ((ks * 32 + kg * 8) ^ ((t & 7) << 3))]);
      }
    const int nb = wv * 128;
#pragma unroll
    for (int at = 0; at < 8; ++at) {
      bf16x8 av[4];
      int arow = nb + at * 16 + lr;
#pragma unroll
      for (int ks = 0; ks < 4; ++ks)
        av[ks] = *(const bf16x8*)(w_inT + arow * 128 + ks * 32 + kg * 8);
#pragma unroll
      for (int jt = 0; jt < 4; ++jt) {
        f32x4 c = {0.f, 0.f, 0.f, 0.f};
#pragma unroll
        for (int ks = 0; ks < 4; ++ks) c = MF(av[ks], bx[jt][ks], c);
        int t = jt * 16 + lr;
        int n0 = nb + at * 16 + kg * 4;
        uint2 p;
        p.x = packbf(c[0], c[1]);
        p.y = packbf(c[2], c[3]);
        *(uint2*)(&xcz[t * 512 + (n0 ^ ((t & 7) << 3))]) = p;
      }
    }
  }
  __syncthreads();

  // causal depthwise conv + bias + silu, chunked x16
  {
    const int d = tid;
    float cw0 = conv_w[d * 4 + 0], cw1 = conv_w[d * 4 + 1];
    float cw2 = conv_w[d * 4 + 2], cw3 = conv_w[d * 4 + 3];
    float cb = conv_b[d];
    float xm3 = 0.f, xm2 = 0.f, xm1 = 0.f;
    for (int c0 = 0; c0 < 64; c0 += 16) {
      float xv[16];
#pragma unroll
      for (int u = 0; u < 16; ++u) {
        int t = c0 + u;
        xv[u] = bf2f(xcz[t * 512 + (d ^ ((t & 7) << 3))]);
      }
#pragma unroll
      for (int u = 0; u < 16; ++u) {
        float sv = fmaf(cw0, xm3, fmaf(cw1, xm2, fmaf(cw2, xm1, fmaf(cw3, xv[u], cb))));
        xm3 = xm2; xm2 = xm1; xm1 = xv[u];
        xv[u] = silu_fast(sv);
      }
#pragma unroll
      for (int u = 0; u < 16; ++u) {
        int t = c0 + u;
        xcz[t * 512 + (d ^ ((t & 7) << 3))] = f2bf(xv[u]);
      }
    }
  }
  __syncthreads();

  // x_proj via MFMA: dbc[t][c] = xc[t][:] . w_xpT[c][:]
  {
    bf16x8 av[8];
    int ta = wv * 16 + lr;
#pragma unroll
    for (int ks = 0; ks < 8; ++ks)
      av[ks] = *(const bf16x8*)(&xcz[ta * 512 + ((ks * 32 + kg * 8) ^ ((ta & 7) << 3))]);
#pragma unroll
    for (int ct = 0; ct < 3; ++ct) {
      f32x4 c = {0.f, 0.f, 0.f, 0.f};
#pragma unroll
      for (int ks = 0; ks < 8; ++ks) {
        bf16x8 bv = *(const bf16x8*)(w_xpT + (ct * 16 + lr) * 256 + ks * 32 + kg * 8);
        c = MF(av[ks], bv, c);
      }
      int tt = wv * 16 + kg * 4;
#pragma unroll
      for (int r = 0; r < 4; ++r)
        dbc[(tt + r) * 48 + ct * 16 + lr] = c[r];
    }
  }
  __syncthreads();

  // selective scan + gate fused (thread = channel d)
  {
    const int d = tid;
    float dtw[8];
#pragma unroll
    for (int r = 0; r < 8; ++r) dtw[r] = dt_w[r * 256 + d];
    const float dtb = dt_b[d];
    float Af2[16];
#pragma unroll
    for (int s2 = 0; s2 < 16; ++s2)
      Af2[s2] = -__builtin_amdgcn_exp2f(Alog[d * 16 + s2] * LOG2E) * LOG2E;
    const float af0l2 = Af2[0];
    bool geo = true;
#pragma unroll
    for (int s2 = 1; s2 < 16; ++s2)
      geo = geo && (fabsf(Af2[s2] - (float)(s2 + 1) * af0l2) <= 2e-4f * fabsf(Af2[s2]));
    const float Dv = Dp[d];

    const int eoff = d;
    const int zoff = 256 + d;

    if (geo) {
      f32x2 h2[8];
#pragma unroll
      for (int k = 0; k < 8; ++k) h2[k] = (f32x2){0.f, 0.f};
#pragma unroll 2
      for (int t = 0; t < 64; ++t) {
        const f32x4* dr4 = (const f32x4*)&dbc[t * 48];
        f32x4 d0 = dr4[0], d1 = dr4[1];
        float dtv = dtb;
        dtv = fmaf(dtw[0], d0[0], dtv); dtv = fmaf(dtw[1], d0[1], dtv);
        dtv = fmaf(dtw[2], d0[2], dtv); dtv = fmaf(dtw[3], d0[3], dtv);
        dtv = fmaf(dtw[4], d1[0], dtv); dtv = fmaf(dtw[5], d1[1], dtv);
        dtv = fmaf(dtw[6], d1[2], dtv); dtv = fmaf(dtw[7], d1[3], dtv);
        dtv = softplus_fast(dtv);
        int sw = (t & 7) << 3;
        int e = t * 512 + (eoff ^ sw);
        float xv = bf2f(xcz[e]);
        float zf = bf2f(xcz[t * 512 + (zoff ^ sw)]);
        float cf = dtv * xv;
        float r1 = __builtin_amdgcn_exp2f(dtv * af0l2);
        float r2 = r1 * r1;
        f32x2 r2v = {r2, r2};
        f32x2 pp = {r1, r2};
        f32x2 cf2 = {cf, cf};
        f32x2 y2 = {0.f, 0.f};
        f32x4 B0 = dr4[2], B1 = dr4[3], B2 = dr4[4], B3 = dr4[5];
        f32x4 C0 = dr4[6], C1 = dr4[7], C2 = dr4[8], C3 = dr4[9];
        f32x2 Bv[8] = {{B0[0],B0[1]},{B0[2],B0[3]},{B1[0],B1[1]},{B1[2],B1[3]},
                       {B2[0],B2[1]},{B2[2],B2[3]},{B3[0],B3[1]},{B3[2],B3[3]}};
        f32x2 Cv[8] = {{C0[0],C0[1]},{C0[2],C0[3]},{C1[0],C1[1]},{C1[2],C1[3]},
                       {C2[0],C2[1]},{C2[2],C2[3]},{C3[0],C3[1]},{C3[2],C3[3]}};
#pragma unroll
        for (int k = 0; k < 8; ++k) {
          h2[k] = __builtin_elementwise_fma(pp, h2[k], cf2 * Bv[k]);
          y2 = __builtin_elementwise_fma(h2[k], Cv[k], y2);
          pp = pp * r2v;
        }
        float y = y2[0] + y2[1];
        xcz[e] = f2bf((fmaf(xv, Dv, y)) * silu_fast(zf));
      }
    } else {
      float h[16];
#pragma unroll
      for (int s2 = 0; s2 < 16; ++s2) h[s2] = 0.f;
#pragma unroll 2
      for (int t = 0; t < 64; ++t) {
        const float* dr = &dbc[t * 48];
        float dtv = dtb;
#pragma unroll
        for (int r = 0; r < 8; ++r) dtv = fmaf(dtw[r], dr[r], dtv);
        dtv = softplus_fast(dtv);
        int sw = (t & 7) << 3;
        int e = t * 512 + (eoff ^ sw);
        float xv = bf2f(xcz[e]);
        float zf = bf2f(xcz[t * 512 + (zoff ^ sw)]);
        float cf = dtv * xv;
        float y = 0.f;
#pragma unroll
        for (int s2 = 0; s2 < 16; ++s2) {
          float dA = __builtin_amdgcn_exp2f(dtv * Af2[s2]);
          h[s2] = fmaf(dA, h[s2], cf * dr[8 + s2]);
          y = fmaf(h[s2], dr[24 + s2], y);
        }
        xcz[e] = f2bf((fmaf(xv, Dv, y)) * silu_fast(zf));
      }
    }
  }
  __syncthreads();

  // GEMM-out via MFMA: y[t][:] . w_outT[c][:]  (wave = t-tile)
  {
    bf16x8 av[8];
    int ta = wv * 16 + lr;
#pragma unroll
    for (int ks = 0; ks < 8; ++ks)
      av[ks] = *(const bf16x8*)(&xcz[ta * 512 + ((ks * 32 + kg * 8) ^ ((ta & 7) << 3))]);
    f32x4 acc[8];
#pragma unroll
    for (int ct = 0; ct < 8; ++ct) {
      f32x4 c = {0.f, 0.f, 0.f, 0.f};
#pragma unroll
      for (int ks = 0; ks < 8; ++ks) {
        bf16x8 bv = *(const bf16x8*)(w_outT + (ct * 16 + lr) * 256 + ks * 32 + kg * 8);
        c = MF(av[ks], bv, c);
      }
      acc[ct] = c;
    }
    size_t ob = (size_t)b * 64 * 512 * 128 + (size_t)(slot_base + n) * 128;
    const int trow = wv * 16 + kg * 4;
    if (s != 1) {
      // node/log: raw y (mix_ffn kernel finishes later)
#pragma unroll
      for (int ct = 0; ct < 8; ++ct) {
        int cc = ct * 16 + lr;
#pragma unroll
        for (int r = 0; r < 4; ++r)
          out[ob + (size_t)(trow + r) * 65536 + cc] = acc[ct][r];
      }
    } else {
      // trace: residual + LN(an[1]) -> t1 (regs), then fused FFN stream 1
      float sum[4] = {0.f, 0.f, 0.f, 0.f}, sq[4] = {0.f, 0.f, 0.f, 0.f};
#pragma unroll
      for (int ct = 0; ct < 8; ++ct) {
        int col = ct * 16 + lr;
#pragma unroll
        for (int r = 0; r < 4; ++r) {
          int t = trow + r;
          float xr = xb[(size_t)t * SEQ * 128 + col];
          float v = acc[ct][r] + xr;
          acc[ct][r] = v;
          sum[r] += v; sq[r] += v * v;
        }
      }
      float mn[4], rstd[4];
#pragma unroll
      for (int r = 0; r < 4; ++r) {
        float s1 = sum[r], s2 = sq[r];
        s1 += __shfl_xor(s1, 1); s2 += __shfl_xor(s2, 1);
        s1 += __shfl_xor(s1, 2); s2 += __shfl_xor(s2, 2);
        s1 += __shfl_xor(s1, 4); s2 += __shfl_xor(s2, 4);
        s1 += __shfl_xor(s1, 8); s2 += __shfl_xor(s2, 8);
        float mean = s1 * (1.f / 128.f);
        float var = s2 * (1.f / 128.f) - mean * mean;
        mn[r] = mean;
        rstd[r] = rsqrtf(var + 1e-5f);
      }
      const float* G  = an_g + 128;
      const float* Bv = an_b + 128;
      // t1 -> xs (bf16, swizzled); dbc is dead, xcz reads all done after barrier
#pragma unroll
      for (int ct = 0; ct < 8; ++ct) {
        int col = ct * 16 + lr;
        float gc = G[col], bc = Bv[col];
#pragma unroll
        for (int r = 0; r < 4; ++r) {
          int t = trow + r;
          float t1 = (acc[ct][r] - mn[r]) * rstd[r] * gc + bc;
          xs[t * 128 + (col ^ ((t & 7) << 3))] = f2bf(t1);
        }
      }
      __syncthreads();

      // ---- fused FFN (stream 1): GEMM1 swapped, hT lives in xcz ----
      const unsigned short* F1 = ff1T + 65536;
      const unsigned short* F2 = ff2T + 65536;
      const float* B1 = fb1 + 512;
      const float* B2 = fb2 + 128;
      const float* FG = fln_g + 128;
      const float* FB = fln_b + 128;
      {
        bf16x8 bx[4][4];
#pragma unroll
        for (int jt = 0; jt < 4; ++jt)
#pragma unroll
          for (int ks = 0; ks < 4; ++ks) {
            int t = jt * 16 + lr;
            bx[jt][ks] = *(const bf16x8*)(&xs[t * 128 + ((ks * 32 + kg * 8) ^ ((t & 7) << 3))]);
          }
        const int nb = wv * 128;
#pragma unroll
        for (int at = 0; at < 8; ++at) {
          bf16x8 av1[4];
          int arow = nb + at * 16 + lr;
#pragma unroll
          for (int ks = 0; ks < 4; ++ks)
            av1[ks] = *(const bf16x8*)(F1 + arow * 128 + ks * 32 + kg * 8);
          float4 bias = *(const float4*)(B1 + nb + at * 16 + kg * 4);
#pragma unroll
          for (int jt = 0; jt < 4; ++jt) {
            f32x4 c = {0.f, 0.f, 0.f, 0.f};
#pragma unroll
            for (int ks = 0; ks < 4; ++ks) c = MF(av1[ks], bx[jt][ks], c);
            float v0 = c[0] + bias.x; v0 = v0 > 0.f ? v0 : 0.01f * v0;
            float v1 = c[1] + bias.y; v1 = v1 > 0.f ? v1 : 0.01f * v1;
            float v2 = c[2] + bias.z; v2 = v2 > 0.f ? v2 : 0.01f * v2;
            float v3 = c[3] + bias.w; v3 = v3 > 0.f ? v3 : 0.01f * v3;
            int t = jt * 16 + lr;
            int n0 = nb + at * 16 + kg * 4;
            uint2 p;
            p.x = packbf(v0, v1);
            p.y = packbf(v2, v3);
            *(uint2*)(&xcz[t * 512 + (n0 ^ ((t & 7) << 3))]) = p;
          }
        }
      }
      __syncthreads();
      {
        bf16x8 av2[16];
        int ta2 = wv * 16 + lr;
#pragma unroll
        for (int ks = 0; ks < 16; ++ks)
          av2[ks] = *(const bf16x8*)(&xcz[ta2 * 512 + ((ks * 32 + kg * 8) ^ ((ta2 & 7) << 3))]);
        f32x4 a2[8];
#pragma unroll
        for (int ct = 0; ct < 8; ++ct) {
          f32x4 c = {0.f, 0.f, 0.f, 0.f};
#pragma unroll
          for (int ks = 0; ks < 16; ++ks) {
            bf16x8 bv = *(const bf16x8*)(F2 + (ct * 16 + lr) * 512 + ks * 32 + kg * 8);
            c = MF(av2[ks], bv, c);
          }
          a2[ct] = c;
        }
        float vv[8][4];
        float su[4] = {0.f, 0.f, 0.f, 0.f}, sb[4] = {0.f, 0.f, 0.f, 0.f};
#pragma unroll
        for (int ct = 0; ct < 8; ++ct) {
          int col = ct * 16 + lr;
          float b2c = B2[col];
#pragma unroll
          for (int r = 0; r < 4; ++r) {
            int t = trow + r;
            float xr = bf2f(xs[t * 128 + (col ^ ((t & 7) << 3))]);
            float val = a2[ct][r] + b2c + xr;
            vv[ct][r] = val;
            su[r] += val; sb[r] += val * val;
          }
        }
        float mn2[4], rs2[4];
#pragma unroll
        for (int r = 0; r < 4; ++r) {
          float s1 = su[r], s2 = sb[r];
          s1 += __shfl_xor(s1, 1); s2 += __shfl_xor(s2, 1);
          s1 += __shfl_xor(s1, 2); s2 += __shfl_xor(s2, 2);
          s1 += __shfl_xor(s1, 4); s2 += __shfl_xor(s2, 4);
          s1 += __shfl_xor(s1, 8); s2 += __shfl_xor(s2, 8);
          float mean = s1 * (1.f / 128.f);
          float var = s2 * (1.f / 128.f) - mean * mean;
          mn2[r] = mean;
          rs2[r] = rsqrtf(var + 1e-5f);
        }
#pragma unroll
        for (int ct = 0; ct < 8; ++ct) {
          int col = ct * 16 + lr;
          float gc = FG[col], bc = FB[col];
#pragma unroll
          for (int r = 0; r < 4; ++r)
            out[ob + (size_t)(trow + r) * 65536 + col] = (vv[ct][r] - mn2[r]) * rs2[r] * gc + bc;
        }
      }
    }
  }
}

// ---------------------------------------------------------------------------
// mix + residual + LN(an) + FULL FFN + LN(fln) for node & log streams.
// One block = one (b,n), 64 w-tokens x {node, log}. 80KB LDS, 2 blocks/CU.
// FFN uses the 2-half split (hT [64][256]).
// ---------------------------------------------------------------------------
__global__ __launch_bounds__(256, 2) void mix_ffn_kernel(
    float* __restrict__ out, const unsigned short* __restrict__ mixT,
    const float* __restrict__ mix_b,
    const float* __restrict__ xn, const float* __restrict__ xl,
    const float* __restrict__ an_g, const float* __restrict__ an_b,
    const unsigned short* __restrict__ ff1T, const float* __restrict__ fb1,
    const unsigned short* __restrict__ ff2T, const float* __restrict__ fb2,
    const float* __restrict__ fln_g, const float* __restrict__ fln_b)
{
  __shared__ __attribute__((aligned(16))) unsigned short cs[64 * 256]; // 32KB
  __shared__ __attribute__((aligned(16))) unsigned short xs[64 * 128]; // 16KB
  __shared__ __attribute__((aligned(16))) unsigned short hT[64 * 256]; // 32KB

  const int tid = threadIdx.x;
  const int lane = tid & 63;
  const int wv = tid >> 6;
  const int lr = lane & 15;
  const int kg = lane >> 4;
  const int bn = blockIdx.x;
  const int b = bn >> 7, n = bn & 127;
  const size_t base_n = (((size_t)b * 64) * 512 + n) * 128;
  const size_t base_l = (((size_t)b * 64) * 512 + 384 + n) * 128;

  for (int idx = tid; idx < 4096; idx += 256) {
    int t = idx >> 6, r = idx & 63;
    int half = r >> 5, qd = (r & 31) << 2;
    const float* src = out + (half ? base_l : base_n) + (size_t)t * 65536 + qd;
    float4 v = *(const float4*)src;
    int col = half * 128 + qd;
    uint2 p;
    p.x = packbf(v.x, v.y);
    p.y = packbf(v.z, v.w);
    *(uint2*)(&cs[t * 256 + (col ^ ((t & 7) << 3))]) = p;
  }
  __syncthreads();

  bf16x8 av[8];
  int ta = wv * 16 + lr;
#pragma unroll
  for (int ks = 0; ks < 8; ++ks)
    av[ks] = *(const bf16x8*)(&cs[ta * 256 + ((ks * 32 + kg * 8) ^ ((ta & 7) << 3))]);

  const int trow = wv * 16 + kg * 4;
#pragma unroll
  for (int half = 0; half < 2; ++half) {
    const int sf = half ? 2 : 0;       // ffn stream index
    const float* xres_base = half ? xl : xn;
    // ---- mix GEMM + silu + residual + LN(an) -> n1 into xs ----
    f32x4 acc[8];
#pragma unroll
    for (int ct = 0; ct < 8; ++ct) {
      f32x4 c = {0.f, 0.f, 0.f, 0.f};
      int colg = half * 128 + ct * 16 + lr;
#pragma unroll
      for (int ks = 0; ks < 8; ++ks) {
        bf16x8 bv = *(const bf16x8*)(mixT + colg * 256 + ks * 32 + kg * 8);
        c = MF(av[ks], bv, c);
      }
      acc[ct] = c;
    }
    float sum[4] = {0.f, 0.f, 0.f, 0.f}, sq[4] = {0.f, 0.f, 0.f, 0.f};
#pragma unroll
    for (int ct = 0; ct < 8; ++ct) {
      int col = ct * 16 + lr;
      int colg = half * 128 + col;
      float bcol = mix_b[colg];
#pragma unroll
      for (int r = 0; r < 4; ++r) {
        int t = trow + r;
        float orig = bf2f(cs[t * 256 + (colg ^ ((t & 7) << 3))]);
        float xr = xres_base[(((size_t)b * 64 + t) * 128 + n) * 128 + col];
        float v = orig + silu_fast(acc[ct][r] + bcol) + xr;
        acc[ct][r] = v;
        sum[r] += v; sq[r] += v * v;
      }
    }
    float mn[4], rstd[4];
#pragma unroll
    for (int r = 0; r < 4; ++r) {
      float s1 = sum[r], s2 = sq[r];
      s1 += __shfl_xor(s1, 1); s2 += __shfl_xor(s2, 1);
      s1 += __shfl_xor(s1, 2); s2 += __shfl_xor(s2, 2);
      s1 += __shfl_xor(s1, 4); s2 += __shfl_xor(s2, 4);
      s1 += __shfl_xor(s1, 8); s2 += __shfl_xor(s2, 8);
      float mean = s1 * (1.f / 128.f);
      float var = s2 * (1.f / 128.f) - mean * mean;
      mn[r] = mean;
      rstd[r] = rsqrtf(var + 1e-5f);
    }
    {
      const float* G  = an_g + (half ? 256 : 0);
      const float* Bv = an_b + (half ? 256 : 0);
#pragma unroll
      for (int ct = 0; ct < 8; ++ct) {
        int col = ct * 16 + lr;
        float gc = G[col], bc = Bv[col];
#pragma unroll
        for (int r = 0; r < 4; ++r) {
          int t = trow + r;
          float n1 = (acc[ct][r] - mn[r]) * rstd[r] * gc + bc;
          xs[t * 128 + (col ^ ((t & 7) << 3))] = f2bf(n1);
        }
      }
    }
    __syncthreads();

    // ---- FFN (2-half split): GEMM1 -> hT -> GEMM2 accum ----
    const unsigned short* F1 = ff1T + (size_t)sf * 65536;
    const unsigned short* F2 = ff2T + (size_t)sf * 65536;
    const float* B1 = fb1 + sf * 512;
    const float* B2 = fb2 + sf * 128;
    const float* FG = fln_g + sf * 128;
    const float* FB = fln_b + sf * 128;

    bf16x8 bx[4][4];
#pragma unroll
    for (int jt = 0; jt < 4; ++jt)
#pragma unroll
      for (int ks = 0; ks < 4; ++ks) {
        int t = jt * 16 + lr;
        bx[jt][ks] = *(const bf16x8*)(&xs[t * 128 + ((ks * 32 + kg * 8) ^ ((t & 7) << 3))]);
      }

    f32x4 acc2[8];
#pragma unroll
    for (int ct = 0; ct < 8; ++ct) acc2[ct] = (f32x4){0.f, 0.f, 0.f, 0.f};

#pragma unroll
    for (int kh = 0; kh < 2; ++kh) {
      const int nb = kh * 256 + wv * 64;
#pragma unroll
      for (int at = 0; at < 4; ++at) {
        bf16x8 av1[4];
        int arow = nb + at * 16 + lr;
#pragma unroll
        for (int ks = 0; ks < 4; ++ks)
          av1[ks] = *(const bf16x8*)(F1 + arow * 128 + ks * 32 + kg * 8);
        float4 bias = *(const float4*)(B1 + nb + at * 16 + kg * 4);
#pragma unroll
        for (int jt = 0; jt < 4; ++jt) {
          f32x4 c = {0.f, 0.f, 0.f, 0.f};
#pragma unroll
          for (int ks = 0; ks < 4; ++ks) c = MF(av1[ks], bx[jt][ks], c);
          float v0 = c[0] + bias.x; v0 = v0 > 0.f ? v0 : 0.01f * v0;
          float v1 = c[1] + bias.y; v1 = v1 > 0.f ? v1 : 0.01f * v1;
          float v2 = c[2] + bias.z; v2 = v2 > 0.f ? v2 : 0.01f * v2;
          float v3 = c[3] + bias.w; v3 = v3 > 0.f ? v3 : 0.01f * v3;
          int t = jt * 16 + lr;
          int nl = wv * 64 + at * 16 + kg * 4;
          uint2 p;
          p.x = packbf(v0, v1);
          p.y = packbf(v2, v3);
          *(uint2*)(&hT[t * 256 + (nl ^ ((t & 7) << 3))]) = p;
        }
      }
      __syncthreads();

      bf16x8 av2[8];
#pragma unroll
      for (int ks = 0; ks < 8; ++ks)
        av2[ks] = *(const bf16x8*)(&hT[ta * 256 + ((ks * 32 + kg * 8) ^ ((ta & 7) << 3))]);
#pragma unroll
      for (int ct = 0; ct < 8; ++ct) {
        f32x4 c = acc2[ct];
#pragma unroll
        for (int ks = 0; ks < 8; ++ks) {
          bf16x8 bv = *(const bf16x8*)(F2 + (ct * 16 + lr) * 512 + kh * 256 + ks * 32 + kg * 8);
          c = MF(av2[ks], bv, c);
        }
        acc2[ct] = c;
      }
      __syncthreads();
    }

    // ---- FFN epilogue: + b2 + n1, LN(fln) -> final write ----
    {
      float vv[8][4];
      float su[4] = {0.f, 0.f, 0.f, 0.f}, sb[4] = {0.f, 0.f, 0.f, 0.f};
#pragma unroll
      for (int ct = 0; ct < 8; ++ct) {
        int col = ct * 16 + lr;
        float b2c = B2[col];
#pragma unroll
        for (int r = 0; r < 4; ++r) {
          int t = trow + r;
          float xr = bf2f(xs[t * 128 + (col ^ ((t & 7) << 3))]);
          float val = acc2[ct][r] + b2c + xr;
          vv[ct][r] = val;
          su[r] += val; sb[r] += val * val;
        }
      }
      float mn2[4], rs2[4];
#pragma unroll
      for (int r = 0; r < 4; ++r) {
        float s1 = su[r], s2 = sb[r];
        s1 += __shfl_xor(s1, 1); s2 += __shfl_xor(s2, 1);
        s1 += __shfl_xor(s1, 2); s2 += __shfl_xor(s2, 2);
        s1 += __shfl_xor(s1, 4); s2 += __shfl_xor(s2, 4);
        s1 += __shfl_xor(s1, 8); s2 += __shfl_xor(s2, 8);
        float mean = s1 * (1.f / 128.f);
        float var = s2 * (1.f / 128.f) - mean * mean;
        mn2[r] = mean;
        rs2[r] = rsqrtf(var + 1e-5f);
      }
      size_t base = half ? base_l : base_n;
#pragma unroll
      for (int ct = 0; ct < 8; ++ct) {
        int col = ct * 16 + lr;
        float gc = FG[col], bc = FB[col];
#pragma unroll
        for (int r = 0; r < 4; ++r)
          out[base + (size_t)(trow + r) * 65536 + col] = (vv[ct][r] - mn2[r]) * rs2[r] * gc + bc;
      }
    }
    __syncthreads();   // xs/hT reuse safe for next half
  }
}

extern "C" void kernel_launch(void* const* d_in, const int* in_sizes, int n_in,
                              void* d_out, int out_size, void* d_ws, size_t ws_size,
                              hipStream_t stream) {
  (void)in_sizes; (void)n_in; (void)out_size; (void)ws_size;
  const float* x_node  = (const float*)d_in[0];
  const float* x_trace = (const float*)d_in[1];
  const float* x_log   = (const float*)d_in[2];
  const float* mp_in     = (const float*)d_in[3];
  const float* mp_conv_w = (const float*)d_in[4];
  const float* mp_conv_b = (const float*)d_in[5];
  const float* mp_xproj  = (const float*)d_in[6];
  const float* mp_dt_w   = (const float*)d_in[7];
  const float* mp_dt_b   = (const float*)d_in[8];
  const float* mp_Alog   = (const float*)d_in[9];
  const float* mp_D      = (const float*)d_in[10];
  const float* mp_out    = (const float*)d_in[11];
  const float* mix_w = (const float*)d_in[12];
  const float* mix_b = (const float*)d_in[13];
  const float* an_g  = (const float*)d_in[14];
  const float* an_b  = (const float*)d_in[15];
  const float* ff1_w = (const float*)d_in[16];
  const float* ff1_b = (const float*)d_in[17];
  const float* ff2_w = (const float*)d_in[18];
  const float* ff2_b = (const float*)d_in[19];
  const float* fln_g = (const float*)d_in[20];
  const float* fln_b = (const float*)d_in[21];
  float* out = (float*)d_out;

  unsigned short* ws = (unsigned short*)d_ws;

  prep_kernel<<<(WS_TOTAL + 255) / 256, 256, 0, stream>>>(
      mp_in, mp_xproj, mp_out, ff1_w, ff2_w, mix_w, ws);

  mamba_front<<<4096, 256, 0, stream>>>(
      x_node, x_trace, x_log,
      ws + WS_WINT, mp_conv_w, mp_conv_b, ws + WS_WXPT,
      mp_dt_w, mp_dt_b, mp_Alog, mp_D, ws + WS_WOUTT,
      an_g, an_b,
      ws + WS_FF1T, ff1_b, ws + WS_FF2T, ff2_b, fln_g, fln_b,
      out);

  mix_ffn_kernel<<<1024, 256, 0, stream>>>(
      out, ws + WS_MIXT, mix_b, x_node, x_log, an_g, an_b,
      ws + WS_FF1T, ff1_b, ws + WS_FF2T, ff2_b, fln_g, fln_b);
}